// Round 6
// baseline (128.120 us; speedup 1.0000x reference)
//
#include <hip/hip_runtime.h>

#define BB 16
#define NN 100000
#define KK 8
#define BLOCK 256

#define ROW_U4 8                              // padded row: 8 uint4 = 128B (48 bf16 + 16B pad)
#define DT_BYTES ((size_t)NN * 128)           // 12.8 MB
#define GRID1 ((NN + 63) / 64)                // 1563 blocks, 64 vertices each
#define TPV 8                                 // 8 lanes cover one 128B row: 2 full lines
#define GRID2 (NN * TPV / BLOCK)              // 3125 blocks exactly (800000 threads)
#define SCALE (1.0f / ((float)BB * NN * 3))

// round-to-nearest-even f32 -> bf16, packed pair
__device__ __forceinline__ unsigned pk_bf16(float a, float b) {
    unsigned ua = __float_as_uint(a), ub = __float_as_uint(b);
    ua = (ua + 0x7FFFu + ((ua >> 16) & 1u)) >> 16;
    ub = (ub + 0x7FFFu + ((ub >> 16) & 1u)) >> 16;
    return ua | (ub << 16);
}

// a[0..7] += wv * unpack8(u)
__device__ __forceinline__ void fma8(float* a, uint4 u, float wv) {
    a[0] += wv * __uint_as_float(u.x << 16);
    a[1] += wv * __uint_as_float(u.x & 0xFFFF0000u);
    a[2] += wv * __uint_as_float(u.y << 16);
    a[3] += wv * __uint_as_float(u.y & 0xFFFF0000u);
    a[4] += wv * __uint_as_float(u.z << 16);
    a[5] += wv * __uint_as_float(u.z & 0xFFFF0000u);
    a[6] += wv * __uint_as_float(u.w << 16);
    a[7] += wv * __uint_as_float(u.w & 0xFFFF0000u);
}

// ---------- Kernel 1: coalesced diff + LDS transpose + bf16 pack (128B rows) ----------
// dT[n][b*3+c] (bf16, 48 data + 16 zero-pad per row)
__global__ __launch_bounds__(BLOCK) void diff_transpose_bf16_kernel(
    const float4* __restrict__ geom4,
    const float4* __restrict__ gtp4,
    uint4*        __restrict__ dT4,
    unsigned*     __restrict__ counter)
{
    __shared__ float tile[64][49];   // [vertex in block][b*3+c], +1 pad
    int tid = threadIdx.x;
    int b = tid >> 4;                // 0..15
    int q = tid & 15;                // n-quad within block
    int nbase = blockIdx.x * 64;
    int n0 = nbase + q * 4;

    if (blockIdx.x == 0 && tid == 0) *counter = 0u;   // reset for kernel 2

    if (n0 < NN) {
        int fi = (b * (NN * 3) + n0 * 3) >> 2;        // float4 index, coalesced
        float4 g0 = geom4[fi], g1 = geom4[fi + 1], g2 = geom4[fi + 2];
        float4 t0 = gtp4[fi],  t1 = gtp4[fi + 1],  t2 = gtp4[fi + 2];
        float d[12] = {g0.x - t0.x, g0.y - t0.y, g0.z - t0.z, g0.w - t0.w,
                       g1.x - t1.x, g1.y - t1.y, g1.z - t1.z, g1.w - t1.w,
                       g2.x - t2.x, g2.y - t2.y, g2.z - t2.z, g2.w - t2.w};
        #pragma unroll
        for (int e = 0; e < 12; ++e)
            tile[q * 4 + e / 3][b * 3 + e % 3] = d[e];
    }
    __syncthreads();

    // 64 rows x 8 uint4 per row = 512 fully-coalesced 16B stores (2 per thread)
    #pragma unroll
    for (int i = 0; i < 2; ++i) {
        int t2 = i * BLOCK + tid;            // 0..511
        int r = t2 >> 3, m = t2 & 7;
        int n = nbase + r;
        if (n < NN) {
            uint4 o;
            if (m < 6) {
                const float* row = &tile[r][m * 8];
                o.x = pk_bf16(row[0], row[1]);
                o.y = pk_bf16(row[2], row[3]);
                o.z = pk_bf16(row[4], row[5]);
                o.w = pk_bf16(row[6], row[7]);
            } else {
                o.x = o.y = o.z = o.w = 0u;  // 32B zero pad
            }
            dT4[n * ROW_U4 + m] = o;
        }
    }
}

// ---------- Kernel 2: 8 threads/vertex gather + reduce (last block finishes) ----------
__global__ __launch_bounds__(BLOCK) void lap_gather_reduce_kernel(
    const uint4* __restrict__ dv,
    const int*   __restrict__ idx,
    const float* __restrict__ w,
    float*       __restrict__ partial,
    unsigned*    __restrict__ counter,
    float*       __restrict__ out)
{
    int t = blockIdx.x * BLOCK + threadIdx.x;  // 800000 threads, no tail
    int n = t >> 3;
    int s = t & 7;                  // which uint4 of the 128B row (6,7 = pad)

    float a[8];
    #pragma unroll
    for (int i = 0; i < 8; ++i) a[i] = 0.0f;

    fma8(a, dv[n * ROW_U4 + s], 1.0f);         // self term, fully coalesced

    const int4*   ip = reinterpret_cast<const int4*>(idx + (size_t)n * KK);
    const float4* wp = reinterpret_cast<const float4*>(w + (size_t)n * KK);
    int4   i0 = ip[0], i1 = ip[1];             // broadcast across 8-lane group
    float4 w0 = wp[0], w1 = wp[1];
    int   js[KK] = {i0.x, i0.y, i0.z, i0.w, i1.x, i1.y, i1.z, i1.w};
    float wk[KK] = {w0.x, w0.y, w0.z, w0.w, w1.x, w1.y, w1.z, w1.w};

    // 8 independent 16B gathers; each quad = one full aligned 64B line
    #pragma unroll
    for (int k = 0; k < KK; ++k)
        fma8(a, dv[js[k] * ROW_U4 + s], wk[k]);

    float ssq = 0.0f;
    #pragma unroll
    for (int i = 0; i < 8; ++i) ssq += a[i] * a[i];

    #pragma unroll
    for (int off = 32; off > 0; off >>= 1)
        ssq += __shfl_down(ssq, off, 64);

    __shared__ float wsum[BLOCK / 64];
    __shared__ int   isLast;
    int lane = threadIdx.x & 63;
    int wid  = threadIdx.x >> 6;
    if (lane == 0) wsum[wid] = ssq;
    __syncthreads();

    if (threadIdx.x == 0) {
        float bs = wsum[0] + wsum[1] + wsum[2] + wsum[3];
        partial[blockIdx.x] = bs;
        __threadfence();
        unsigned old = atomicAdd(counter, 1u);
        isLast = (old == (unsigned)(GRID2 - 1));
    }
    __syncthreads();

    if (isLast) {
        __threadfence();   // acquire: see all blocks' partial[] stores
        float s2 = 0.0f;
        for (int i = threadIdx.x; i < GRID2; i += BLOCK)
            s2 += partial[i];
        #pragma unroll
        for (int off = 32; off > 0; off >>= 1)
            s2 += __shfl_down(s2, off, 64);
        __syncthreads();                 // wsum reuse hazard
        if (lane == 0) wsum[wid] = s2;
        __syncthreads();
        if (threadIdx.x == 0)
            out[0] = (wsum[0] + wsum[1] + wsum[2] + wsum[3]) * SCALE;
    }
}

extern "C" void kernel_launch(void* const* d_in, const int* in_sizes, int n_in,
                              void* d_out, int out_size, void* d_ws, size_t ws_size,
                              hipStream_t stream) {
    const float* geom = (const float*)d_in[0];
    const float* gtp  = (const float*)d_in[1];
    const int*   idx  = (const int*)d_in[2];
    const float* w    = (const float*)d_in[3];
    float* out = (float*)d_out;

    uint4*    dT4     = (uint4*)d_ws;
    unsigned* counter = (unsigned*)((char*)d_ws + DT_BYTES);
    float*    partial = (float*)((char*)d_ws + DT_BYTES + 64);

    diff_transpose_bf16_kernel<<<GRID1, BLOCK, 0, stream>>>(
        (const float4*)geom, (const float4*)gtp, dT4, counter);
    lap_gather_reduce_kernel<<<GRID2, BLOCK, 0, stream>>>(
        dT4, idx, w, partial, counter, out);
}

// Round 7
// 32.434 us; speedup vs baseline: 3.9502x; 3.9502x over previous
//
#include <hip/hip_runtime.h>

#define BB 16
#define NN 100000
#define KK 8
#define BLOCK 256

#define ROW_U4 8                              // padded row: 8 uint4 = 128B (48 bf16 + 16B pad)
#define DT_BYTES ((size_t)NN * 128)           // 12.8 MB
#define GRID1 ((NN + 63) / 64)                // 1563 blocks, 64 vertices each
#define TPV 8                                 // 8 lanes cover one 128B row: 2 full aligned lines
#define GRID2 (NN * TPV / BLOCK)              // 3125 blocks exactly (800000 threads, no tail)
#define SCALE (1.0f / ((float)BB * NN * 3))

// round-to-nearest-even f32 -> bf16, packed pair
__device__ __forceinline__ unsigned pk_bf16(float a, float b) {
    unsigned ua = __float_as_uint(a), ub = __float_as_uint(b);
    ua = (ua + 0x7FFFu + ((ua >> 16) & 1u)) >> 16;
    ub = (ub + 0x7FFFu + ((ub >> 16) & 1u)) >> 16;
    return ua | (ub << 16);
}

// a[0..7] += wv * unpack8(u)
__device__ __forceinline__ void fma8(float* a, uint4 u, float wv) {
    a[0] += wv * __uint_as_float(u.x << 16);
    a[1] += wv * __uint_as_float(u.x & 0xFFFF0000u);
    a[2] += wv * __uint_as_float(u.y << 16);
    a[3] += wv * __uint_as_float(u.y & 0xFFFF0000u);
    a[4] += wv * __uint_as_float(u.z << 16);
    a[5] += wv * __uint_as_float(u.z & 0xFFFF0000u);
    a[6] += wv * __uint_as_float(u.w << 16);
    a[7] += wv * __uint_as_float(u.w & 0xFFFF0000u);
}

// ---------- Kernel 1: coalesced diff + LDS transpose + bf16 pack (128B rows) ----------
// dT[n][b*3+c] (bf16, 48 data + 16 zero-pad per row) = geom[b][n][c] - gtp[b][n][c]
__global__ __launch_bounds__(BLOCK) void diff_transpose_bf16_kernel(
    const float4* __restrict__ geom4,
    const float4* __restrict__ gtp4,
    uint4*        __restrict__ dT4)
{
    __shared__ float tile[64][49];   // [vertex in block][b*3+c], +1 pad
    int tid = threadIdx.x;
    int b = tid >> 4;                // 0..15
    int q = tid & 15;                // n-quad within block
    int nbase = blockIdx.x * 64;
    int n0 = nbase + q * 4;

    if (n0 < NN) {
        int fi = (b * (NN * 3) + n0 * 3) >> 2;        // float4 index, coalesced
        float4 g0 = geom4[fi], g1 = geom4[fi + 1], g2 = geom4[fi + 2];
        float4 t0 = gtp4[fi],  t1 = gtp4[fi + 1],  t2 = gtp4[fi + 2];
        float d[12] = {g0.x - t0.x, g0.y - t0.y, g0.z - t0.z, g0.w - t0.w,
                       g1.x - t1.x, g1.y - t1.y, g1.z - t1.z, g1.w - t1.w,
                       g2.x - t2.x, g2.y - t2.y, g2.z - t2.z, g2.w - t2.w};
        #pragma unroll
        for (int e = 0; e < 12; ++e)
            tile[q * 4 + e / 3][b * 3 + e % 3] = d[e];
    }
    __syncthreads();

    // 64 rows x 8 uint4 per row = 512 fully-coalesced 16B stores (2 per thread)
    #pragma unroll
    for (int i = 0; i < 2; ++i) {
        int t2 = i * BLOCK + tid;            // 0..511
        int r = t2 >> 3, m = t2 & 7;
        int n = nbase + r;
        if (n < NN) {
            uint4 o;
            if (m < 6) {
                const float* row = &tile[r][m * 8];
                o.x = pk_bf16(row[0], row[1]);
                o.y = pk_bf16(row[2], row[3]);
                o.z = pk_bf16(row[4], row[5]);
                o.w = pk_bf16(row[6], row[7]);
            } else {
                o.x = o.y = o.z = o.w = 0u;  // 32B zero pad
            }
            dT4[n * ROW_U4 + m] = o;
        }
    }
}

// ---------- Kernel 2: 8 threads/vertex gather; plain per-block partial store ----------
__global__ __launch_bounds__(BLOCK) void lap_gather_kernel(
    const uint4* __restrict__ dv,
    const int*   __restrict__ idx,
    const float* __restrict__ w,
    float*       __restrict__ partial)
{
    int t = blockIdx.x * BLOCK + threadIdx.x;  // 800000 threads, no tail
    int n = t >> 3;
    int s = t & 7;                  // which uint4 of the 128B row (6,7 = pad)

    float a[8];
    #pragma unroll
    for (int i = 0; i < 8; ++i) a[i] = 0.0f;

    fma8(a, dv[n * ROW_U4 + s], 1.0f);         // self term, fully coalesced

    const int4*   ip = reinterpret_cast<const int4*>(idx + (size_t)n * KK);
    const float4* wp = reinterpret_cast<const float4*>(w + (size_t)n * KK);
    int4   i0 = ip[0], i1 = ip[1];             // broadcast across 8-lane group
    float4 w0 = wp[0], w1 = wp[1];
    int   js[KK] = {i0.x, i0.y, i0.z, i0.w, i1.x, i1.y, i1.z, i1.w};
    float wk[KK] = {w0.x, w0.y, w0.z, w0.w, w1.x, w1.y, w1.z, w1.w};

    // 8 independent 16B gathers; each quad = one full aligned 64B line
    #pragma unroll
    for (int k = 0; k < KK; ++k)
        fma8(a, dv[js[k] * ROW_U4 + s], wk[k]);

    float ssq = 0.0f;
    #pragma unroll
    for (int i = 0; i < 8; ++i) ssq += a[i] * a[i];

    #pragma unroll
    for (int off = 32; off > 0; off >>= 1)
        ssq += __shfl_down(ssq, off, 64);

    __shared__ float wsum[BLOCK / 64];
    int lane = threadIdx.x & 63;
    int wid  = threadIdx.x >> 6;
    if (lane == 0) wsum[wid] = ssq;
    __syncthreads();

    if (threadIdx.x == 0)
        partial[blockIdx.x] = wsum[0] + wsum[1] + wsum[2] + wsum[3];
    // NO __threadfence, NO atomics: agent-scope fences trigger per-XCD L2
    // writeback/invalidate on gfx950 and were costing ~30ns x 3125 blocks
    // plus 2-4x dT re-fetch (R4-R6 post-mortem).
}

// ---------- Kernel 3: tiny final reduce, overwrites out (no zeroing needed) ----------
__global__ __launch_bounds__(BLOCK) void final_reduce_kernel(
    const float* __restrict__ partial,
    float*       __restrict__ out)
{
    float s = 0.0f;
    for (int i = threadIdx.x; i < GRID2; i += BLOCK)
        s += partial[i];

    #pragma unroll
    for (int off = 32; off > 0; off >>= 1)
        s += __shfl_down(s, off, 64);

    __shared__ float wsum[BLOCK / 64];
    int lane = threadIdx.x & 63;
    int wid  = threadIdx.x >> 6;
    if (lane == 0) wsum[wid] = s;
    __syncthreads();

    if (threadIdx.x == 0)
        out[0] = (wsum[0] + wsum[1] + wsum[2] + wsum[3]) * SCALE;
}

extern "C" void kernel_launch(void* const* d_in, const int* in_sizes, int n_in,
                              void* d_out, int out_size, void* d_ws, size_t ws_size,
                              hipStream_t stream) {
    const float* geom = (const float*)d_in[0];
    const float* gtp  = (const float*)d_in[1];
    const int*   idx  = (const int*)d_in[2];
    const float* w    = (const float*)d_in[3];
    float* out = (float*)d_out;

    uint4* dT4     = (uint4*)d_ws;
    float* partial = (float*)((char*)d_ws + DT_BYTES);

    diff_transpose_bf16_kernel<<<GRID1, BLOCK, 0, stream>>>(
        (const float4*)geom, (const float4*)gtp, dT4);
    lap_gather_kernel<<<GRID2, BLOCK, 0, stream>>>(dT4, idx, w, partial);
    final_reduce_kernel<<<1, BLOCK, 0, stream>>>(partial, out);
}